// Round 10
// baseline (300.110 us; speedup 1.0000x reference)
//
#include <hip/hip_runtime.h>
#include <hip/hip_bf16.h>

// ---------------------------------------------------------------------------
// MoE dense all-expert forward, MI355X / gfx950.  B=16384, D=H=O=256, E=32.
// Round 14: 4 waves/SIMD TLP (pipe-overlap fix).
//  R12/R13 post-mortem: three ILP grafts all flat at ~211us, MfmaUtil ~29%.
//  Per-CU per-k-step demands: MFMA 256cyc + LDS 285cyc + L2 292cyc; measured
//  step 960cyc = the SERIAL SUM -> pipes not overlapping at 2 waves/SIMD.
//  Fix is TLP, not ILP: 1024 threads (16 waves, 4/SIMD), 2 crews x 8 waves,
//  wave owns 32 cols x ALL 64 rows:
//   - weight traffic unchanged (stream per wave, fetched once per block);
//   - regs sized for the hard 128-cap (R1-R3 law): acc 32 (AGPR) +
//     A-ring[4] 16 + B-ring[2]x2 16 + addressing ~= 105 live, no spill;
//   - LDS reads double (B-frag read by 8 waves/crew): LDS-bound floor
//     ~95us < current 211us.
//  Unchanged: crew0 GEMM1(e) from x_s, crew1 GEMM2(e-1) from h_s dbuf,
//  one s_barrier/phase with lgkmcnt-only drain, bumped stream pointers
//  (imm-foldable refill offsets), setprio around MFMAs.
// ---------------------------------------------------------------------------

typedef __attribute__((ext_vector_type(8))) short bf16x8;   // 8 bf16 = 4 VGPRs
typedef __attribute__((ext_vector_type(4))) float f32x4;
typedef __attribute__((ext_vector_type(16))) float f32x16;  // 32x32 C frag

__device__ __forceinline__ unsigned short f2bf(float f) {
    unsigned u = __builtin_bit_cast(unsigned, f);
    u += 0x7FFFu + ((u >> 16) & 1u);        // round-to-nearest-even
    return (unsigned short)(u >> 16);
}
__device__ __forceinline__ unsigned pack_bf16x2(float a, float b) {
    return (unsigned)f2bf(a) | ((unsigned)f2bf(b) << 16);
}

// 16B-chunk XOR swizzle for [64 rows][256 elem] bf16 tiles (index in ushorts)
#define LX(r, ch) (((r) << 8) + ((((ch) ^ ((r) & 7))) << 3))

// ------------------- W f32 -> bf16 convert + tile reorder ------------------
// Stream s = m*8 + cg: m=0 -> W1 rows cg*32..+31, m=1 -> W2 rows cg*32..+31.
// Per stream: 33 experts (e=32 is prefetch-overrun pad) x 16 k-step chunks.
// Chunk = 512 bf16 = 1 KB, element (lane, j): row = cg*32 + (lane&31),
// k = ks*16 + (lane>>5)*8 + j  — the mfma_32x32x16 A-frag order.
__global__ __launch_bounds__(256) void cvt_w(const float* __restrict__ W1,
                                             const float* __restrict__ W2,
                                             unsigned short* __restrict__ Wr) {
    int T = blockIdx.x * 256 + threadIdx.x;          // 524288 threads
    int lane = T & 63, ks = (T >> 6) & 15, e = (T >> 10) & 31;
    int cg = (T >> 15) & 7, m = (T >> 18) & 1;
    int l31 = lane & 31, hi = lane >> 5;
    const float* src = (m ? W2 : W1) +
                       ((long)e * 256 + cg * 32 + l31) * 256 + ks * 16 + hi * 8;
    float4 v0 = ((const float4*)src)[0], v1 = ((const float4*)src)[1];
    uint4 o;
    o.x = pack_bf16x2(v0.x, v0.y); o.y = pack_bf16x2(v0.z, v0.w);
    o.z = pack_bf16x2(v1.x, v1.y); o.w = pack_bf16x2(v1.z, v1.w);
    long U = (((long)(m * 8 + cg) * 33 + e) * 16 + ks) * 64 + lane;
    ((uint4*)Wr)[U] = o;
}

#define MFMA32(A, B, C) __builtin_amdgcn_mfma_f32_32x32x16_bf16(A, B, C, 0, 0, 0)

// One k-step, static j in 0..7 within an 8-step group (global step = g8*8+j):
//  - consume A-ring slot j&3 (loaded 4 steps ago), refill from bumped ptr
//  - consume B-ring slot j&1 (loaded 2 steps ago), refill for step j+2
//    (tail refills wrap via &31 -> in-bounds garbage, never consumed)
//  - 2 MFMAs (rows 0-31 and 32-63 of the wave's 32 output cols)
#define GSTEP(j, BUF) do {                                                     \
    bf16x8 a = ra[(j) & 3];                                                    \
    ra[(j) & 3] = *(const bf16x8*)(pla + ((j) & 3) * 512);                     \
    bf16x8 b0 = cba[(j) & 1], b1 = cbb[(j) & 1];                               \
    cba[(j) & 1] = *(const bf16x8*)(&(BUF)[LX(l31,      (ckn + ((j) + 2) * 2) & 31)]); \
    cbb[(j) & 1] = *(const bf16x8*)(&(BUF)[LX(32 + l31, (ckn + ((j) + 2) * 2) & 31)]); \
    __builtin_amdgcn_s_setprio(1);                                             \
    acc0 = MFMA32(a, b0, acc0);                                                \
    acc1 = MFMA32(a, b1, acc1);                                                \
    __builtin_amdgcn_s_setprio(0);                                             \
    if (((j) & 3) == 3) { pla += 2048; }                                       \
} while (0)

// Epilogue for one row-group: +b1, relu, *gate, pack -> h_s[e&1]
#define EPI(ACC, RG) do {                                                      \
    const int rr = (RG) * 32 + l31;                                            \
    const float gw = gws[rr * 33 + e];                                         \
    const int rbase = rr << 8, rsw = rr & 7;                                   \
    _Pragma("unroll")                                                          \
    for (int q = 0; q < 4; ++q) {                                              \
        float4 bv = *(const float4*)(bias1 + e * 256 + cg * 32 + q * 8 + hi * 4); \
        float v0 = fmaxf(ACC[4 * q + 0] + bv.x, 0.f) * gw;                     \
        float v1 = fmaxf(ACC[4 * q + 1] + bv.y, 0.f) * gw;                     \
        float v2 = fmaxf(ACC[4 * q + 2] + bv.z, 0.f) * gw;                     \
        float v3 = fmaxf(ACC[4 * q + 3] + bv.w, 0.f) * gw;                     \
        uint2 pk;                                                              \
        pk.x = pack_bf16x2(v0, v1);                                            \
        pk.y = pack_bf16x2(v2, v3);                                            \
        int ch = cg * 4 + q;                                                   \
        *(uint2*)(&hw[rbase + ((ch ^ rsw) << 3) + hi * 4]) = pk;               \
    }                                                                          \
} while (0)

__global__ __launch_bounds__(1024)
__attribute__((amdgpu_waves_per_eu(4, 4)))
void moe_kernel(
    const float* __restrict__ x,
    const unsigned short* __restrict__ Wr,
    const float* __restrict__ bias1,
    const float* __restrict__ b2,
    const float* __restrict__ Wg,
    const float* __restrict__ bg,
    float* __restrict__ out)
{
    __shared__ __align__(16) unsigned short x_s[64 * 256];      // 32 KB
    __shared__ __align__(16) unsigned short h_s[2][64 * 256];   // 64 KB dbuf
    __shared__ float gws[64 * 33];                              // gate weights

    const int tid  = threadIdx.x;
    const int wv   = tid >> 6, lane = tid & 63;
    const int l31  = lane & 31, hi = lane >> 5;
    const int crew = wv >> 3;                   // 0 = GEMM1, 1 = GEMM2
    const int cg   = wv & 7;                    // cols cg*32 .. cg*32+31
    const int row0 = blockIdx.x * 64;

    // ---- stage x tile: f32 global -> bf16 LDS (swizzled) ----
#pragma unroll
    for (int c = 0; c < 2; ++c) {
        int chunk = tid + c * 1024;             // 2048 chunks of 8 elems
        int r = chunk >> 5, ch = chunk & 31;
        const float4* s = (const float4*)(x + (long)(row0 + r) * 256 + ch * 8);
        float4 v0 = s[0], v1 = s[1];
        uint4 o;
        o.x = pack_bf16x2(v0.x, v0.y); o.y = pack_bf16x2(v0.z, v0.w);
        o.z = pack_bf16x2(v1.x, v1.y); o.w = pack_bf16x2(v1.z, v1.w);
        *(uint4*)(&x_s[LX(r, ch)]) = o;
    }

    // ---- inline gating: 4 rows per wave, all f32 (matches reference) ----
    {
        const int e32 = lane & 31, half = lane >> 5;
        const float4* wg4 = (const float4*)(Wg + e32 * 256 + half * 128);
        float bgv = bg[e32];
        for (int i = 0; i < 4; ++i) {
            int lr = wv * 4 + i;
            const float4* xr4 = (const float4*)(x + (long)(row0 + lr) * 256 + half * 128);
            float acc = 0.f;
#pragma unroll
            for (int tt = 0; tt < 32; ++tt) {
                float4 w = wg4[tt], xv = xr4[tt];
                acc = fmaf(w.x, xv.x, acc); acc = fmaf(w.y, xv.y, acc);
                acc = fmaf(w.z, xv.z, acc); acc = fmaf(w.w, xv.w, acc);
            }
            acc += __shfl_xor(acc, 32);
            float score = (acc + bgv) / 2.71828182845904523f;   // TEMP = e

            float m = score;
#pragma unroll
            for (int d = 16; d >= 1; d >>= 1) m = fmaxf(m, __shfl_xor(m, d));
            float p_ = expf(score - m);
            float ps = p_;
#pragma unroll
            for (int d = 16; d >= 1; d >>= 1) ps += __shfl_xor(ps, d);
            float prob = p_ / ps;

            int rank = 0;
#pragma unroll
            for (int j = 0; j < 32; ++j) {
                float pj = __shfl(prob, j);
                rank += (pj > prob || (pj == prob && j < e32)) ? 1 : 0;
            }
            float kept = (rank < 22) ? prob : 0.f;
            float wsum = kept;
#pragma unroll
            for (int d = 16; d >= 1; d >>= 1) wsum += __shfl_xor(wsum, d);
            float weight = kept / (wsum + 1e-8f);

            if (half == 0) gws[lr * 33 + e32] = weight;
        }
    }

    __syncthreads();   // x_s + gws ready

    // ---- weight stream (one per wave): crew0 -> W1 cg; crew1 -> W2 cg ----
    const unsigned short* ws =
        Wr + (long)(crew * 8 + cg) * (33 * 16 * 512) + lane * 8;
    bf16x8 ra[4];
#pragma unroll
    for (int t = 0; t < 4; ++t) ra[t] = *(const bf16x8*)(ws + t * 512);
    const unsigned short* pla = ws + 4 * 512;   // next chunk to load (4 ahead)

    // ---- B-frag register ring (depth 2, static indices) ----
    bf16x8 cba[2], cbb[2];

    // ---- accumulators: crew0 hacc (re-zeroed per phase); crew1 oacc ----
    f32x16 acc0, acc1;                          // rows 0-31 / rows 32-63
#pragma unroll
    for (int i = 0; i < 16; ++i) { acc0[i] = 0.f; acc1[i] = 0.f; }
    if (crew == 1) {
        for (int ee = 0; ee < 32; ++ee) {
            float gv0 = gws[l31 * 33 + ee];
            float gv1 = gws[(32 + l31) * 33 + ee];
#pragma unroll
            for (int q = 0; q < 4; ++q) {
                float4 bb = *(const float4*)(b2 + ee * 256 + cg * 32 + q * 8 + hi * 4);
                acc0[4 * q + 0] = fmaf(gv0, bb.x, acc0[4 * q + 0]);
                acc0[4 * q + 1] = fmaf(gv0, bb.y, acc0[4 * q + 1]);
                acc0[4 * q + 2] = fmaf(gv0, bb.z, acc0[4 * q + 2]);
                acc0[4 * q + 3] = fmaf(gv0, bb.w, acc0[4 * q + 3]);
                acc1[4 * q + 0] = fmaf(gv1, bb.x, acc1[4 * q + 0]);
                acc1[4 * q + 1] = fmaf(gv1, bb.y, acc1[4 * q + 1]);
                acc1[4 * q + 2] = fmaf(gv1, bb.z, acc1[4 * q + 2]);
                acc1[4 * q + 3] = fmaf(gv1, bb.w, acc1[4 * q + 3]);
            }
        }
    }

    // ---- expert pipeline: crew0 GEMM1(e), crew1 GEMM2(e-1), 1 barrier ----
#pragma unroll 1
    for (int e = 0; e <= 32; ++e) {
        if (crew == 0) {
            if (e < 32) {
#pragma unroll
                for (int i = 0; i < 16; ++i) { acc0[i] = 0.f; acc1[i] = 0.f; }
                // B-ring prologue: frags for steps 0,1
#pragma unroll
                for (int t = 0; t < 2; ++t) {
                    cba[t] = *(const bf16x8*)(&x_s[LX(l31,      t * 2 + hi)]);
                    cbb[t] = *(const bf16x8*)(&x_s[LX(32 + l31, t * 2 + hi)]);
                }
#pragma unroll 1
                for (int g8 = 0; g8 < 2; ++g8) {
                    const int ckn = g8 * 16 + hi;
                    GSTEP(0, x_s); GSTEP(1, x_s); GSTEP(2, x_s); GSTEP(3, x_s);
                    GSTEP(4, x_s); GSTEP(5, x_s); GSTEP(6, x_s); GSTEP(7, x_s);
                }
                // epilogue: +b1, relu, *gate -> h_s[e&1]
                unsigned short* hw = h_s[e & 1];
                EPI(acc0, 0);
                EPI(acc1, 1);
            }
        } else {
            if (e >= 1) {
                const unsigned short* hbr = h_s[(e + 1) & 1];  // h(e-1)
#pragma unroll
                for (int t = 0; t < 2; ++t) {
                    cba[t] = *(const bf16x8*)(&hbr[LX(l31,      t * 2 + hi)]);
                    cbb[t] = *(const bf16x8*)(&hbr[LX(32 + l31, t * 2 + hi)]);
                }
#pragma unroll 1
                for (int g8 = 0; g8 < 2; ++g8) {
                    const int ckn = g8 * 16 + hi;
                    GSTEP(0, hbr); GSTEP(1, hbr); GSTEP(2, hbr); GSTEP(3, hbr);
                    GSTEP(4, hbr); GSTEP(5, hbr); GSTEP(6, hbr); GSTEP(7, hbr);
                }
            }
        }

        // barrier with LDS-only drain: weight prefetches stay in flight
        asm volatile("s_waitcnt lgkmcnt(0)" ::: "memory");
        __builtin_amdgcn_s_barrier();
    }

    // ---- final store (crew1): out = acc0/acc1 ----
    if (crew == 1) {
#pragma unroll
        for (int q = 0; q < 4; ++q) {
            f32x4 s0 = {acc0[4 * q + 0], acc0[4 * q + 1],
                        acc0[4 * q + 2], acc0[4 * q + 3]};
            f32x4 s1 = {acc1[4 * q + 0], acc1[4 * q + 1],
                        acc1[4 * q + 2], acc1[4 * q + 3]};
            *(f32x4*)(out + (long)(row0 + l31) * 256 +
                      cg * 32 + q * 8 + hi * 4) = s0;
            *(f32x4*)(out + (long)(row0 + 32 + l31) * 256 +
                      cg * 32 + q * 8 + hi * 4) = s1;
        }
    }
}

// ------------------------------- launch ------------------------------------
extern "C" void kernel_launch(void* const* d_in, const int* in_sizes, int n_in,
                              void* d_out, int out_size, void* d_ws, size_t ws_size,
                              hipStream_t stream) {
    (void)in_sizes; (void)n_in; (void)out_size; (void)ws_size;
    const float* x  = (const float*)d_in[0];   // [16384,256]
    const float* W1 = (const float*)d_in[1];   // [32,256,256]
    const float* b1 = (const float*)d_in[2];   // [32,256]
    const float* W2 = (const float*)d_in[3];   // [32,256,256]
    const float* b2 = (const float*)d_in[4];   // [32,256]
    const float* Wg = (const float*)d_in[5];   // [32,256]
    const float* bg = (const float*)d_in[6];   // [32]
    float* out = (float*)d_out;                // [16384,256]

    // ws: Wr = 16 streams x 33 experts x 16 KB = 8.25 MiB (expert 32 = pad)
    unsigned short* Wr = (unsigned short*)d_ws;

    cvt_w<<<2048, 256, 0, stream>>>(W1, W2, Wr);
    moe_kernel<<<256, 1024, 0, stream>>>(x, Wr, b1, b2, Wg, bg, out);
}